// Round 7
// baseline (459.529 us; speedup 1.0000x reference)
//
#include <hip/hip_runtime.h>
#include <hip/hip_bf16.h>
#include <cstdint>
#include <cstddef>

// Problem constants
#define BB   512
#define NN   100
#define HH   768
#define II   1536
#define MM   (BB*NN)          // 51200 rows

typedef __bf16 bf16;
typedef __bf16 bf16x4 __attribute__((ext_vector_type(4)));
typedef __bf16 bf16x8 __attribute__((ext_vector_type(8)));
typedef float  f32x4  __attribute__((ext_vector_type(4)));

// async global -> LDS, 16B per lane (wave-uniform LDS base + lane*16)
__device__ __forceinline__ void gld_lds16(const void* g, void* l) {
    __builtin_amdgcn_global_load_lds(
        (const __attribute__((address_space(1))) void*)g,
        (__attribute__((address_space(3))) void*)l, 16, 0, 0);
}

// butterfly add over 16-lane groups via ds_swizzle (BitMode, single DS inst)
template <int PAT>
__device__ __forceinline__ float swz_add(float x) {
    return x + __int_as_float(
        __builtin_amdgcn_ds_swizzle(__float_as_int(x), PAT));
}
__device__ __forceinline__ float red16(float x) {
    x = swz_add<0x041F>(x);   // xor 1
    x = swz_add<0x081F>(x);   // xor 2
    x = swz_add<0x101F>(x);   // xor 4
    x = swz_add<0x201F>(x);   // xor 8
    return x;                 // all 16 lanes hold the group sum
}

// Fast exact-GELU: erf via Abramowitz-Stegun 7.1.26 (|err| <= 1.5e-7)
__device__ __forceinline__ float fast_gelu(float x) {
    const float ax = fabsf(x) * 0.70710678118654752f;   // |x|/sqrt(2)
    const float t  = __builtin_amdgcn_rcpf(fmaf(0.3275911f, ax, 1.0f));
    float p = fmaf(1.061405429f, t, -1.453152027f);
    p = fmaf(p, t, 1.421413741f);
    p = fmaf(p, t, -0.284496736f);
    p = fmaf(p, t, 0.254829592f);
    p = p * t;
    const float e    = __expf(-ax * ax);
    const float erfa = fmaf(-p, e, 1.0f);               // erf(|x|/sqrt2)
    const float erfx = copysignf(erfa, x);
    return 0.5f * x * (1.0f + erfx);
}

// ---------------------------------------------------------------------------
// prep: W1 fp32 [768][1536] -> Wp bf16 [1536][768] via LDS tile transpose
// (coalesced reads AND writes); gw = gamma*W2; scal = {S1, S2}
// Grid: 288 transpose tiles (64k x 64n) + 2 tail blocks.
// ---------------------------------------------------------------------------
__global__ __launch_bounds__(256) void prep_kernel(
    const float* __restrict__ W1, const float* __restrict__ gamma,
    const float* __restrict__ beta, const float* __restrict__ W2,
    const float* __restrict__ b2,
    bf16* __restrict__ Wp, float* __restrict__ gw, float* __restrict__ scal)
{
    const int bid = blockIdx.x, tid = threadIdx.x;
    if (bid < 288) {
        __shared__ bf16 Ts[64 * 72];     // 64n x 64k, pad 8
        const int kt = bid % 12, nt = bid / 12;
        const int k0 = kt * 64, n0 = nt * 64;
        #pragma unroll
        for (int it = 0; it < 4; ++it) {
            const int idx = it * 256 + tid;          // 0..1023
            const int r   = idx >> 4;                // k-row 0..63
            const int c4  = idx & 15;                // n float4 0..15
            float4 v = *(const float4*)&W1[(size_t)(k0 + r) * II + n0 + c4*4];
            Ts[(c4*4 + 0) * 72 + r] = (bf16)v.x;
            Ts[(c4*4 + 1) * 72 + r] = (bf16)v.y;
            Ts[(c4*4 + 2) * 72 + r] = (bf16)v.z;
            Ts[(c4*4 + 3) * 72 + r] = (bf16)v.w;
        }
        __syncthreads();
        #pragma unroll
        for (int it = 0; it < 2; ++it) {
            const int idx = it * 256 + tid;          // 0..511
            const int nr  = idx >> 3;                // n-row 0..63
            const int kc  = idx & 7;                 // k-octet 0..7
            *(bf16x8*)&Wp[(size_t)(n0 + nr) * HH + k0 + kc*8]
                = *(const bf16x8*)&Ts[nr * 72 + kc*8];
        }
    } else if (bid == 288) {
        for (int j = tid; j < II; j += 256)
            gw[j] = gamma[j] * W2[j];
    } else {
        float s1 = 0.f, s2 = 0.f;
        for (int j = tid; j < II; j += 256) {
            float w2 = W2[j];
            s1 += gamma[j] * w2;
            s2 += beta[j]  * w2;
        }
        #pragma unroll
        for (int off = 32; off; off >>= 1) {
            s1 += __shfl_down(s1, off, 64);
            s2 += __shfl_down(s2, off, 64);
        }
        __shared__ float a1[4], a2[4];
        int lane = tid & 63, w = tid >> 6;
        if (lane == 0) { a1[w] = s1; a2[w] = s2; }
        __syncthreads();
        if (tid == 0) {
            scal[0] = a1[0] + a1[1] + a1[2] + a1[3];
            scal[1] = a2[0] + a2[1] + a2[2] + a2[3] + b2[0];
        }
    }
}

// ---------------------------------------------------------------------------
// gemm_part: 128x128 tile, BK=64, 16x16x32 bf16 MFMA.
// A staged ASYNC as raw fp32 (global_load_lds, 32 KB), pair-swizzled:
//   pair p (8 floats) of row r stored at slot p^(r&7), two 16B halves.
// bf16 conversion happens at fragment read (2x ds_read_b128 + pack cvt).
// B staged async as bf16 (16 KB, 8-elem slot swizzle g^(r&7)).
// sred aliased onto Bs after the K-loop -> LDS = 48 KB -> 3 blocks/CU.
// XCD swizzle: 12 col-blocks sharing an A-tile run on one XCD.
// ---------------------------------------------------------------------------
__global__ __launch_bounds__(256) void gemm_part(
    const float* __restrict__ Af, const bf16* __restrict__ Wp,
    const float* __restrict__ b1, const float* __restrict__ gw,
    float* __restrict__ part)
{
    __shared__ float AsF[128 * 64];     // 32 KB
    __shared__ bf16  Bs[128 * 64];      // 16 KB

    const int tid  = threadIdx.x;
    // XCD swizzle: 4800 blocks = 8 XCDs x 600; 600 = 50 mb x 12 nb
    const int lin  = (blockIdx.x % 8) * 600 + blockIdx.x / 8;
    const int mb   = lin / 12;
    const int nb   = lin % 12;
    const int lane = tid & 63;
    const int w    = tid >> 6;
    const int wm   = w >> 1;            // 0..1
    const int wn   = w & 1;             // 0..1
    const int m15  = lane & 15;
    const int q    = lane >> 4;         // 0..3
    const int row0 = mb * 128;

    // --- A staging (fp32): 8 chunks of 16 rows; r=tid>>4, halfpair h=tid&15
    const int ar = tid >> 4;                       // 0..15
    const int h  = tid & 15;
    const int ap = h >> 1;                         // pair 0..7
    const int asl = ap ^ (ar & 7);                 // stored slot
    const float* aP = Af + (size_t)(row0 + ar) * HH + asl * 8 + (h & 1) * 4;

    // --- B staging (bf16): 4 chunks of 32 rows; r=tid>>3, slot tid&7
    const int br = tid >> 3;                       // 0..31
    const int bsl = (tid & 7) ^ (br & 7);
    const bf16* bP = Wp + (size_t)(nb*128 + br) * HH + bsl * 8;

    f32x4 acc[4][4] = {};

    for (int kt = 0; kt < 12; ++kt) {
        #pragma unroll
        for (int it = 0; it < 4; ++it)
            gld_lds16(bP + (size_t)it * 32 * HH, &Bs[tid*8 + it*2048]);
        #pragma unroll
        for (int it = 0; it < 8; ++it)
            gld_lds16(aP + (size_t)it * 16 * HH, &AsF[tid*4 + it*1024]);
        asm volatile("s_waitcnt vmcnt(0)" ::: "memory");
        __syncthreads();

        #pragma unroll
        for (int kb = 0; kb < 2; ++kb) {
            const int pk_ = kb * 4 + q;
            bf16x8 af[4], bfr[4];
            #pragma unroll
            for (int mt = 0; mt < 4; ++mt) {
                const int rr = wm*64 + mt*16 + m15;
                const int fb = rr * 64 + (pk_ ^ (rr & 7)) * 8;
                f32x4 lo = *(const f32x4*)&AsF[fb];
                f32x4 hi = *(const f32x4*)&AsF[fb + 4];
                af[mt] = bf16x8{ (bf16)lo[0], (bf16)lo[1], (bf16)lo[2],
                                 (bf16)lo[3], (bf16)hi[0], (bf16)hi[1],
                                 (bf16)hi[2], (bf16)hi[3] };
            }
            const int swz = (pk_ ^ (m15 & 7)) * 8;
            #pragma unroll
            for (int nt = 0; nt < 4; ++nt)
                bfr[nt] = *(const bf16x8*)&Bs[(wn*64 + nt*16 + m15) * 64 + swz];
            #pragma unroll
            for (int mt = 0; mt < 4; ++mt)
                #pragma unroll
                for (int nt = 0; nt < 4; ++nt)
                    acc[mt][nt] = __builtin_amdgcn_mfma_f32_16x16x32_bf16(
                        af[mt], bfr[nt], acc[mt][nt], 0, 0, 0);
        }
        __syncthreads();
        aP += 64; bP += 64;
    }

    // epilogue: +b1, fast GELU, per-row partial stats over this block's cols
    float* sred = (float*)Bs;    // [wn][rl][s] = wn*384 + rl*3 + s (Bs dead)

    float bv[4], gv[4];
    #pragma unroll
    for (int nt = 0; nt < 4; ++nt) {
        const int col = nb*128 + wn*64 + nt*16 + m15;
        bv[nt] = b1[col];
        gv[nt] = gw[col];
    }

    #pragma unroll
    for (int mt = 0; mt < 4; ++mt) {
        #pragma unroll
        for (int r = 0; r < 4; ++r) {
            float x0 = 0.f, x1 = 0.f, x2 = 0.f;
            #pragma unroll
            for (int nt = 0; nt < 4; ++nt) {
                // C/D layout: col = lane&15, row = q*4 + r
                float g = fast_gelu(acc[mt][nt][r] + bv[nt]);
                x0 += g; x1 += g * g; x2 += g * gv[nt];
            }
            x0 = red16(x0); x1 = red16(x1); x2 = red16(x2);
            if (m15 == 0) {
                const int rl = wm*64 + mt*16 + q*4 + r;   // 0..127
                sred[wn*384 + rl*3 + 0] = x0;
                sred[wn*384 + rl*3 + 1] = x1;
                sred[wn*384 + rl*3 + 2] = x2;
            }
        }
    }
    __syncthreads();

    if (tid < 128) {
        const size_t rg = (size_t)row0 + tid;
        #pragma unroll
        for (int s = 0; s < 3; ++s)
            part[(size_t)s * 12 * MM + (size_t)nb * MM + rg]
                = sred[0*384 + tid*3 + s] + sred[1*384 + tid*3 + s];
    }
}

// ---------------------------------------------------------------------------
// score_pred: finish LN + sigmoid for the 100 rows of batch b, write scores,
// then pred = sum(scores), logits = one_hot(clamp(round(pred),0,15))
// ---------------------------------------------------------------------------
__global__ __launch_bounds__(128) void score_pred(
    const float* __restrict__ part, const float* __restrict__ scal,
    float* __restrict__ o_scores, float* __restrict__ o_pred,
    float* __restrict__ o_logits)
{
    const int b = blockIdx.x, t = threadIdx.x;
    float s = 0.f;
    if (t < NN) {
        const size_t row = (size_t)b * NN + t;
        float Sh = 0.f, Shh = 0.f, Shg = 0.f;
        #pragma unroll
        for (int j = 0; j < 12; ++j) {
            Sh  += part[(size_t)0*12*MM + (size_t)j*MM + row];
            Shh += part[(size_t)1*12*MM + (size_t)j*MM + row];
            Shg += part[(size_t)2*12*MM + (size_t)j*MM + row];
        }
        const float mu   = Sh * (1.0f / II);
        const float var  = Shh * (1.0f / II) - mu * mu;
        const float rstd = rsqrtf(var + 1e-5f);
        const float z    = rstd * (Shg - mu * scal[0]) + scal[1];
        s = 1.0f / (1.0f + __expf(-z));
        o_scores[row] = s;
    }
    float v = s;
    #pragma unroll
    for (int off = 32; off; off >>= 1) v += __shfl_down(v, off, 64);
    __shared__ float ssum[2];
    const int lane = t & 63, w = t >> 6;
    if (lane == 0) ssum[w] = v;
    __syncthreads();
    const float p = ssum[0] + ssum[1];
    if (t == 0) o_pred[b] = p;
    if (t < 16) {
        int aid = (int)rintf(p);
        aid = aid < 0 ? 0 : (aid > 15 ? 15 : aid);
        o_logits[b * 16 + t] = (t == aid) ? 1.0f : 0.0f;
    }
}

// ---------------------------------------------------------------------------
extern "C" void kernel_launch(void* const* d_in, const int* in_sizes, int n_in,
                              void* d_out, int out_size, void* d_ws, size_t ws_size,
                              hipStream_t stream)
{
    const float* v_emb = (const float*)d_in[0];
    const float* W1    = (const float*)d_in[1];
    const float* b1    = (const float*)d_in[2];
    const float* gamma = (const float*)d_in[3];
    const float* beta  = (const float*)d_in[4];
    const float* W2    = (const float*)d_in[5];
    const float* b2    = (const float*)d_in[6];

    char* ws = (char*)d_ws;
    size_t off = 0;
    bf16*  Wp   = (bf16*)(ws + off);  off += (size_t)II * HH * 2;      // 2.36 MB
    float* gw   = (float*)(ws + off); off += (size_t)II * 4;
    float* scal = (float*)(ws + off); off += 256;
    float* part = (float*)(ws + off); off += (size_t)MM * 36 * 4;      // 7.37 MB

    float* out       = (float*)d_out;
    float* o_scores  = out;            // 51200
    float* o_pred    = out + MM;       // 512
    float* o_logits  = out + MM + BB;  // 8192

    hipLaunchKernelGGL(prep_kernel, dim3(290), dim3(256), 0, stream,
                       W1, gamma, beta, W2, b2, Wp, gw, scal);
    hipLaunchKernelGGL(gemm_part, dim3((MM / 128) * 12), dim3(256),
                       0, stream, v_emb, Wp, b1, gw, part);
    hipLaunchKernelGGL(score_pred, dim3(BB), dim3(128), 0, stream,
                       part, scal, o_scores, o_pred, o_logits);
}

// Round 8
// 428.052 us; speedup vs baseline: 1.0735x; 1.0735x over previous
//
#include <hip/hip_runtime.h>
#include <hip/hip_bf16.h>
#include <cstdint>
#include <cstddef>

// Problem constants
#define BB   512
#define NN   100
#define HH   768
#define II   1536
#define MM   (BB*NN)          // 51200 rows

typedef __bf16 bf16;
typedef __bf16 bf16x4 __attribute__((ext_vector_type(4)));
typedef __bf16 bf16x8 __attribute__((ext_vector_type(8)));
typedef float  f32x4  __attribute__((ext_vector_type(4)));

// async global -> LDS, 16B per lane (wave-uniform LDS base + lane*16)
__device__ __forceinline__ void gld_lds16(const void* g, void* l) {
    __builtin_amdgcn_global_load_lds(
        (const __attribute__((address_space(1))) void*)g,
        (__attribute__((address_space(3))) void*)l, 16, 0, 0);
}

// butterfly add over 16-lane groups via ds_swizzle (BitMode, single DS inst)
template <int PAT>
__device__ __forceinline__ float swz_add(float x) {
    return x + __int_as_float(
        __builtin_amdgcn_ds_swizzle(__float_as_int(x), PAT));
}
__device__ __forceinline__ float red16(float x) {
    x = swz_add<0x041F>(x);   // xor 1
    x = swz_add<0x081F>(x);   // xor 2
    x = swz_add<0x101F>(x);   // xor 4
    x = swz_add<0x201F>(x);   // xor 8
    return x;                 // all 16 lanes hold the group sum
}

// Fast exact-GELU: erf via Abramowitz-Stegun 7.1.26 (|err| <= 1.5e-7)
__device__ __forceinline__ float fast_gelu(float x) {
    const float ax = fabsf(x) * 0.70710678118654752f;   // |x|/sqrt(2)
    const float t  = __builtin_amdgcn_rcpf(fmaf(0.3275911f, ax, 1.0f));
    float p = fmaf(1.061405429f, t, -1.453152027f);
    p = fmaf(p, t, 1.421413741f);
    p = fmaf(p, t, -0.284496736f);
    p = fmaf(p, t, 0.254829592f);
    p = p * t;
    const float e    = __expf(-ax * ax);
    const float erfa = fmaf(-p, e, 1.0f);               // erf(|x|/sqrt2)
    const float erfx = copysignf(erfa, x);
    return 0.5f * x * (1.0f + erfx);
}

// ---------------------------------------------------------------------------
// prep: one launch does everything the gemm needs:
//   bid <  288 : W1 fp32 [768][1536] -> Wp bf16 [1536][768] (LDS transpose)
//   bid == 288 : gw = gamma*W2
//   bid == 289 : scal = {S1 = sum gamma*W2, S2 = sum beta*W2 + b2}
//   bid >= 290 : pack v_emb fp32 -> Apk bf16 [51200][768] (9600 blocks)
// ---------------------------------------------------------------------------
__global__ __launch_bounds__(256) void prep_kernel(
    const float* __restrict__ W1, const float* __restrict__ gamma,
    const float* __restrict__ beta, const float* __restrict__ W2,
    const float* __restrict__ b2, const float* __restrict__ A,
    bf16* __restrict__ Wp, float* __restrict__ gw, float* __restrict__ scal,
    bf16* __restrict__ Apk)
{
    const int bid = blockIdx.x, tid = threadIdx.x;
    if (bid >= 290) {
        // A-pack: 9600 blocks x 4 iters x 256 threads x float4
        const size_t base = (size_t)(bid - 290) * 4096 + tid * 4;
        #pragma unroll
        for (int it = 0; it < 4; ++it) {
            const size_t i = base + it * 1024;
            float4 v = *(const float4*)&A[i];
            bf16x4 o = { (bf16)v.x, (bf16)v.y, (bf16)v.z, (bf16)v.w };
            *(bf16x4*)&Apk[i] = o;
        }
    } else if (bid < 288) {
        __shared__ bf16 Ts[64 * 72];     // 64n x 64k, pad 8
        const int kt = bid % 12, nt = bid / 12;
        const int k0 = kt * 64, n0 = nt * 64;
        #pragma unroll
        for (int it = 0; it < 4; ++it) {
            const int idx = it * 256 + tid;          // 0..1023
            const int r   = idx >> 4;                // k-row 0..63
            const int c4  = idx & 15;                // n float4 0..15
            float4 v = *(const float4*)&W1[(size_t)(k0 + r) * II + n0 + c4*4];
            Ts[(c4*4 + 0) * 72 + r] = (bf16)v.x;
            Ts[(c4*4 + 1) * 72 + r] = (bf16)v.y;
            Ts[(c4*4 + 2) * 72 + r] = (bf16)v.z;
            Ts[(c4*4 + 3) * 72 + r] = (bf16)v.w;
        }
        __syncthreads();
        #pragma unroll
        for (int it = 0; it < 2; ++it) {
            const int idx = it * 256 + tid;          // 0..511
            const int nr  = idx >> 3;                // n-row 0..63
            const int kc  = idx & 7;                 // k-octet 0..7
            *(bf16x8*)&Wp[(size_t)(n0 + nr) * HH + k0 + kc*8]
                = *(const bf16x8*)&Ts[nr * 72 + kc*8];
        }
    } else if (bid == 288) {
        for (int j = tid; j < II; j += 256)
            gw[j] = gamma[j] * W2[j];
    } else {
        float s1 = 0.f, s2 = 0.f;
        for (int j = tid; j < II; j += 256) {
            float w2 = W2[j];
            s1 += gamma[j] * w2;
            s2 += beta[j]  * w2;
        }
        #pragma unroll
        for (int off = 32; off; off >>= 1) {
            s1 += __shfl_down(s1, off, 64);
            s2 += __shfl_down(s2, off, 64);
        }
        __shared__ float a1[4], a2[4];
        int lane = tid & 63, w = tid >> 6;
        if (lane == 0) { a1[w] = s1; a2[w] = s2; }
        __syncthreads();
        if (tid == 0) {
            scal[0] = a1[0] + a1[1] + a1[2] + a1[3];
            scal[1] = a2[0] + a2[1] + a2[2] + a2[3] + b2[0];
        }
    }
}

// ---------------------------------------------------------------------------
// gemm_part: 128x128 tile, BK=64, 16x16x32 bf16 MFMA (R5 proven staging:
// both operands bf16, async global_load_lds, 8-slot XOR swizzle -> 0 bank
// conflicts). sred aliased onto dead As -> LDS 32 KB -> 5 blocks/CU.
// XCD swizzle: 12 col-blocks sharing an A-tile run on one XCD.
// Epilogue: +b1, fast GELU, per-row partial LN stats -> part[s][nb][row].
// ---------------------------------------------------------------------------
__global__ __launch_bounds__(256) void gemm_part(
    const bf16* __restrict__ Apk, const bf16* __restrict__ Wp,
    const float* __restrict__ b1, const float* __restrict__ gw,
    float* __restrict__ part)
{
    __shared__ bf16 As[128 * 64];      // 16 KB
    __shared__ bf16 Bs[128 * 64];      // 16 KB

    const int tid  = threadIdx.x;
    // XCD swizzle: 4800 blocks = 8 XCDs x 600; 600 = 50 mb x 12 nb
    const int lin  = (blockIdx.x % 8) * 600 + blockIdx.x / 8;
    const int mb   = lin / 12;
    const int nb   = lin % 12;
    const int lane = tid & 63;
    const int w    = tid >> 6;
    const int wm   = w >> 1;            // 0..1
    const int wn   = w & 1;             // 0..1
    const int m15  = lane & 15;
    const int q    = lane >> 4;         // 0..3
    const int row0 = mb * 128;

    // staging: thread covers row rsub=tid>>3, slot tid&7; slot g holds
    // k-group g^(rsub&7) so lane*16 LDS dest works AND ds_read is 2-way max
    const int rsub  = tid >> 3;                   // 0..31
    const int kg    = (tid & 7) ^ (rsub & 7);
    const int lbase = tid * 8;

    const bf16* aP = Apk + (size_t)(row0    + rsub) * HH + kg * 8;
    const bf16* bP = Wp  + (size_t)(nb*128 + rsub) * HH + kg * 8;

    f32x4 acc[4][4] = {};

    for (int kt = 0; kt < 12; ++kt) {
        #pragma unroll
        for (int it = 0; it < 4; ++it) {
            gld_lds16(aP + (size_t)it * 32 * HH, &As[lbase + it * 2048]);
            gld_lds16(bP + (size_t)it * 32 * HH, &Bs[lbase + it * 2048]);
        }
        asm volatile("s_waitcnt vmcnt(0)" ::: "memory");
        __syncthreads();

        #pragma unroll
        for (int kb = 0; kb < 2; ++kb) {
            const int swz = (((kb * 4 + q) ^ (m15 & 7)) * 8);
            bf16x8 af[4], bfr[4];
            #pragma unroll
            for (int mt = 0; mt < 4; ++mt)
                af[mt] = *(const bf16x8*)&As[(wm*64 + mt*16 + m15) * 64 + swz];
            #pragma unroll
            for (int nt = 0; nt < 4; ++nt)
                bfr[nt] = *(const bf16x8*)&Bs[(wn*64 + nt*16 + m15) * 64 + swz];
            #pragma unroll
            for (int mt = 0; mt < 4; ++mt)
                #pragma unroll
                for (int nt = 0; nt < 4; ++nt)
                    acc[mt][nt] = __builtin_amdgcn_mfma_f32_16x16x32_bf16(
                        af[mt], bfr[nt], acc[mt][nt], 0, 0, 0);
        }
        __syncthreads();
        aP += 64; bP += 64;
    }

    // epilogue: +b1, fast GELU, per-row partial stats over this block's cols
    float* sred = (float*)As;    // As dead after final barrier; 3 KB reuse

    float bv[4], gv[4];
    #pragma unroll
    for (int nt = 0; nt < 4; ++nt) {
        const int col = nb*128 + wn*64 + nt*16 + m15;
        bv[nt] = b1[col];
        gv[nt] = gw[col];
    }

    #pragma unroll
    for (int mt = 0; mt < 4; ++mt) {
        #pragma unroll
        for (int r = 0; r < 4; ++r) {
            float x0 = 0.f, x1 = 0.f, x2 = 0.f;
            #pragma unroll
            for (int nt = 0; nt < 4; ++nt) {
                // C/D layout: col = lane&15, row = q*4 + r
                float g = fast_gelu(acc[mt][nt][r] + bv[nt]);
                x0 += g; x1 += g * g; x2 += g * gv[nt];
            }
            x0 = red16(x0); x1 = red16(x1); x2 = red16(x2);
            if (m15 == 0) {
                const int rl = wm*64 + mt*16 + q*4 + r;   // 0..127
                sred[wn*384 + rl*3 + 0] = x0;
                sred[wn*384 + rl*3 + 1] = x1;
                sred[wn*384 + rl*3 + 2] = x2;
            }
        }
    }
    __syncthreads();

    if (tid < 128) {
        const size_t rg = (size_t)row0 + tid;
        #pragma unroll
        for (int s = 0; s < 3; ++s)
            part[(size_t)s * 12 * MM + (size_t)nb * MM + rg]
                = sred[0*384 + tid*3 + s] + sred[1*384 + tid*3 + s];
    }
}

// ---------------------------------------------------------------------------
// score_pred: finish LN + sigmoid for the 100 rows of batch b, write scores,
// then pred = sum(scores), logits = one_hot(clamp(round(pred),0,15))
// ---------------------------------------------------------------------------
__global__ __launch_bounds__(128) void score_pred(
    const float* __restrict__ part, const float* __restrict__ scal,
    float* __restrict__ o_scores, float* __restrict__ o_pred,
    float* __restrict__ o_logits)
{
    const int b = blockIdx.x, t = threadIdx.x;
    float s = 0.f;
    if (t < NN) {
        const size_t row = (size_t)b * NN + t;
        float Sh = 0.f, Shh = 0.f, Shg = 0.f;
        #pragma unroll
        for (int j = 0; j < 12; ++j) {
            Sh  += part[(size_t)0*12*MM + (size_t)j*MM + row];
            Shh += part[(size_t)1*12*MM + (size_t)j*MM + row];
            Shg += part[(size_t)2*12*MM + (size_t)j*MM + row];
        }
        const float mu   = Sh * (1.0f / II);
        const float var  = Shh * (1.0f / II) - mu * mu;
        const float rstd = rsqrtf(var + 1e-5f);
        const float z    = rstd * (Shg - mu * scal[0]) + scal[1];
        s = 1.0f / (1.0f + __expf(-z));
        o_scores[row] = s;
    }
    float v = s;
    #pragma unroll
    for (int off = 32; off; off >>= 1) v += __shfl_down(v, off, 64);
    __shared__ float ssum[2];
    const int lane = t & 63, w = t >> 6;
    if (lane == 0) ssum[w] = v;
    __syncthreads();
    const float p = ssum[0] + ssum[1];
    if (t == 0) o_pred[b] = p;
    if (t < 16) {
        int aid = (int)rintf(p);
        aid = aid < 0 ? 0 : (aid > 15 ? 15 : aid);
        o_logits[b * 16 + t] = (t == aid) ? 1.0f : 0.0f;
    }
}

// ---------------------------------------------------------------------------
extern "C" void kernel_launch(void* const* d_in, const int* in_sizes, int n_in,
                              void* d_out, int out_size, void* d_ws, size_t ws_size,
                              hipStream_t stream)
{
    const float* v_emb = (const float*)d_in[0];
    const float* W1    = (const float*)d_in[1];
    const float* b1    = (const float*)d_in[2];
    const float* gamma = (const float*)d_in[3];
    const float* beta  = (const float*)d_in[4];
    const float* W2    = (const float*)d_in[5];
    const float* b2    = (const float*)d_in[6];

    char* ws = (char*)d_ws;
    size_t off = 0;
    bf16*  Wp   = (bf16*)(ws + off);  off += (size_t)II * HH * 2;      // 2.36 MB
    float* gw   = (float*)(ws + off); off += (size_t)II * 4;
    float* scal = (float*)(ws + off); off += 256;
    float* part = (float*)(ws + off); off += (size_t)MM * 36 * 4;      // 7.37 MB
    bf16*  Apk  = (bf16*)(ws + off);  off += (size_t)MM * HH * 2;      // 78.6 MB

    float* out       = (float*)d_out;
    float* o_scores  = out;            // 51200
    float* o_pred    = out + MM;       // 512
    float* o_logits  = out + MM + BB;  // 8192

    hipLaunchKernelGGL(prep_kernel, dim3(290 + 9600), dim3(256), 0, stream,
                       W1, gamma, beta, W2, b2, v_emb, Wp, gw, scal, Apk);
    hipLaunchKernelGGL(gemm_part, dim3((MM / 128) * 12), dim3(256),
                       0, stream, Apk, Wp, b1, gw, part);
    hipLaunchKernelGGL(score_pred, dim3(BB), dim3(128), 0, stream,
                       part, scal, o_scores, o_pred, o_logits);
}